// Round 4
// baseline (502.689 us; speedup 1.0000x reference)
//
#include <hip/hip_runtime.h>

#define NB 8
#define PART_STRIDE 522240  // floats per channel-half partial-logit buffer

typedef float f4 __attribute__((ext_vector_type(4)));

__device__ __forceinline__ f4 ntload(const float* p) {
  return __builtin_nontemporal_load((const f4*)p);
}
__device__ __forceinline__ void ntstore(float* p, f4 v) {
  __builtin_nontemporal_store(v, (f4*)p);
}

struct K1Args {
  const float* x[4];
  float* part;          // [2][522240] partial logits
  int N[4];
  int ntiles[4];        // N/512 (min 1)
  int logOff[4];
};

struct K2Args {
  float* part;          // in: two halves; out: expl in half 0
  float* zpart;         // [4][24][16]
  int N[4];
  int ntiles2[4];       // N/1024 (min 1)
  int logOff[4];
};

struct K3Args {
  const float* x[4];
  const float* expl;    // part half 0 (exp'd)
  float* outp[4];
  float* ctx[4];        // raw (unnormalized) sums
  int N[4];
  int logOff[4];
};

// K1: partial logits over a 128-channel half; cached x loads (prime L3 for K3's reuse)
__global__ __launch_bounds__(128) void k1_partdot(K1Args a, const float* __restrict__ wqk_all) {
  int zz = blockIdx.z, lvl = zz >> 1, ch = zz & 1;
  if ((int)blockIdx.x >= a.ntiles[lvl]) return;
  int N = a.N[lvl];
  int bg = blockIdx.y, g = bg % 3, b = bg / 3;
  int n0 = blockIdx.x * 512 + (threadIdx.x << 2);
  if (n0 >= N) return;
  const float* __restrict__ xb = a.x[lvl] + (size_t)b * 768 * N;
  const float* __restrict__ wqk = wqk_all + lvl * 256 + ch * 128;
  f4 acc0 = {0.f, 0.f, 0.f, 0.f};
  f4 acc1 = {0.f, 0.f, 0.f, 0.f};
  int f0 = g * 256 + ch * 128;
#pragma unroll 8
  for (int i = 0; i < 128; i += 2) {
    int f = f0 + i;
    int s0 = (f % 3) * 256 + f / 3;
    int s1 = ((f + 1) % 3) * 256 + (f + 1) / 3;
    f4 v0 = *(const f4*)(xb + (size_t)s0 * N + n0);
    f4 v1 = *(const f4*)(xb + (size_t)s1 * N + n0);
    acc0 += v0 * wqk[i];
    acc1 += v1 * wqk[i + 1];
  }
  *(f4*)(a.part + (size_t)ch * PART_STRIDE + a.logOff[lvl] + (size_t)bg * N + n0) = acc0 + acc1;
}

// K2: expl = exp(part0 + part1) in place (half 0); per-(lvl,bg,tile) Z partial (deterministic)
__global__ __launch_bounds__(256) void k2_exp(K2Args a) {
  int lvl = blockIdx.z;
  if ((int)blockIdx.x >= a.ntiles2[lvl]) return;
  int N = a.N[lvl];
  int bg = blockIdx.y;
  int n0 = blockIdx.x * 1024 + (threadIdx.x << 2);
  float es = 0.f;
  if (n0 < N) {
    size_t off = (size_t)a.logOff[lvl] + (size_t)bg * N + n0;
    float* p0 = a.part + off;
    const float* p1 = a.part + PART_STRIDE + off;
    f4 v0 = *(const f4*)p0;
    f4 v1 = *(const f4*)p1;
    f4 s = v0 + v1;
    f4 e;
    e.x = __expf(s.x);
    e.y = __expf(s.y);
    e.z = __expf(s.z);
    e.w = __expf(s.w);
    *(f4*)p0 = e;
    es = e.x + e.y + e.z + e.w;
  }
  for (int o = 32; o; o >>= 1) es += __shfl_xor(es, o);
  __shared__ float sr[4];
  if ((threadIdx.x & 63) == 0) sr[threadIdx.x >> 6] = es;
  __syncthreads();
  if (threadIdx.x == 0)
    a.zpart[((size_t)lvl * 24 + bg) * 16 + blockIdx.x] = sr[0] + sr[1] + sr[2] + sr[3];
}

// K3: out[b,c2,n] = sum_g x[src(g,c2),n]  (CACHED store -> L3 holds out for K5)
//     ctxraw[b,g,c2] = sum_n x[src(g,c2),n] * expl[b,g,n]  (unnormalized)
//     levels processed in REVERSE order (3->0) to hit the x-tail K1 left in L3
__global__ __launch_bounds__(256) void k3_ctx_out(K3Args a) {
  int lvl = 3 - blockIdx.z;
  int N = a.N[lvl];
  int c2 = blockIdx.x, b = blockIdx.y;
  const float* __restrict__ xb = a.x[lvl] + (size_t)b * 768 * N;
  int f0 = c2, f1 = 256 + c2, f2 = 512 + c2;
  const float* __restrict__ r0 = xb + (size_t)((f0 % 3) * 256 + f0 / 3) * N;
  const float* __restrict__ r1 = xb + (size_t)((f1 % 3) * 256 + f1 / 3) * N;
  const float* __restrict__ r2 = xb + (size_t)((f2 % 3) * 256 + f2 / 3) * N;
  const float* __restrict__ eb = a.expl + a.logOff[lvl];
  const float* __restrict__ e0 = eb + (size_t)(b * 3 + 0) * N;
  const float* __restrict__ e1 = eb + (size_t)(b * 3 + 1) * N;
  const float* __restrict__ e2 = eb + (size_t)(b * 3 + 2) * N;
  float* __restrict__ o = a.outp[lvl] + ((size_t)b * 256 + c2) * N;
  float a0 = 0.f, a1 = 0.f, a2 = 0.f;
#pragma unroll 4
  for (int n = threadIdx.x << 2; n < N; n += 1024) {
    f4 v0 = ntload(r0 + n);
    f4 v1 = ntload(r1 + n);
    f4 v2 = ntload(r2 + n);
    f4 w0 = *(const f4*)(e0 + n);
    f4 w1 = *(const f4*)(e1 + n);
    f4 w2 = *(const f4*)(e2 + n);
    f4 ov = v0 + v1 + v2;
    *(f4*)(o + n) = ov;
    f4 p0 = v0 * w0, p1 = v1 * w1, p2 = v2 * w2;
    a0 += p0.x + p0.y + p0.z + p0.w;
    a1 += p1.x + p1.y + p1.z + p1.w;
    a2 += p2.x + p2.y + p2.z + p2.w;
  }
  for (int o2 = 32; o2; o2 >>= 1) {
    a0 += __shfl_xor(a0, o2);
    a1 += __shfl_xor(a1, o2);
    a2 += __shfl_xor(a2, o2);
  }
  __shared__ float sr[3][4];
  int wv = threadIdx.x >> 6;
  if ((threadIdx.x & 63) == 0) { sr[0][wv] = a0; sr[1][wv] = a1; sr[2][wv] = a2; }
  __syncthreads();
  if (threadIdx.x < 3) {
    int t = threadIdx.x;
    float s = sr[t][0] + sr[t][1] + sr[t][2] + sr[t][3];
    a.ctx[lvl][((size_t)b * 3 + t) * 256 + c2] = s;
  }
}

__device__ __forceinline__ float blk_sum256(float v, float* sr4) {
  for (int o = 32; o; o >>= 1) v += __shfl_xor(v, o);
  __syncthreads();
  if ((threadIdx.x & 63) == 0) sr4[threadIdx.x >> 6] = v;
  __syncthreads();
  return sr4[0] + sr4[1] + sr4[2] + sr4[3];
}

// K4: normalize ctx by Z (from zpart), then ct-MLP + lvl-weight MLP -> add
__global__ __launch_bounds__(256) void k4_mlp(
    const float* __restrict__ ctx_all, const float* __restrict__ zpart,
    const float* __restrict__ ct_w1, const float* __restrict__ ct_b1,
    const float* __restrict__ ct_g,  const float* __restrict__ ct_be,
    const float* __restrict__ ct_w2, const float* __restrict__ ct_b2,
    const float* __restrict__ lw_w1, const float* __restrict__ lw_b1,
    const float* __restrict__ lw_g,  const float* __restrict__ lw_be,
    const float* __restrict__ lw_w2, const float* __restrict__ lw_b2,
    float* __restrict__ add_all) {
  int b = blockIdx.x, lvl = blockIdx.y;
  int t = threadIdx.x;
  const float* cin = ctx_all + ((size_t)lvl * NB + b) * 768;
  const float* w1 = ct_w1 + lvl * 64 * 256;
  const float* b1 = ct_b1 + lvl * 64;
  const float* cg = ct_g + lvl * 64;
  const float* cbe = ct_be + lvl * 64;
  const float* w2 = ct_w2 + lvl * 256 * 64;
  const float* b2 = ct_b2 + lvl * 256;
  const float* W1 = lw_w1 + (size_t)lvl * 768 * 768;
  const float* B1 = lw_b1 + lvl * 768;
  const float* Lg = lw_g + lvl * 768;
  const float* Lbe = lw_be + lvl * 768;
  const float* W2 = lw_w2 + lvl * 3 * 768;
  const float* B2 = lw_b2 + lvl * 3;
  float* addp = add_all + ((size_t)lvl * NB + b) * 256;

  __shared__ float sctx[768];
  __shared__ float sh1[3][64];
  __shared__ float sl1[768];
  __shared__ float slvlw[3];
  __shared__ float sr4[4];
  __shared__ float sZp[48];
  __shared__ float sZ[3];

  int nt = 16 >> (2 * lvl);
  if (nt < 1) nt = 1;
  if (t < 48) {
    int g = t >> 4, i = t & 15;
    sZp[t] = (i < nt) ? zpart[((size_t)lvl * 24 + b * 3 + g) * 16 + i] : 0.f;
  }
  __syncthreads();
  if (t < 3) {
    float z = 0.f;
#pragma unroll
    for (int i = 0; i < 16; ++i) z += sZp[t * 16 + i];
    sZ[t] = z;
  }
  __syncthreads();
  for (int i = t; i < 768; i += 256) sctx[i] = cin[i] / sZ[i >> 8];
  __syncthreads();

  if (t < 192) {
    int g = t >> 6, j = t & 63;
    float acc = b1[j];
    const float* w = w1 + j * 256;
    const float* c = sctx + g * 256;
#pragma unroll 4
    for (int k = 0; k < 256; ++k) acc = fmaf(c[k], w[k], acc);
    sh1[g][j] = acc;
  }
  __syncthreads();
  int wv = t >> 6, ln = t & 63;
  if (wv < 3) {
    float v = sh1[wv][ln];
    float s = v;
    for (int o = 32; o; o >>= 1) s += __shfl_xor(s, o);
    float mean = s * (1.f / 64.f);
    float d = v - mean;
    float q = d * d;
    for (int o = 32; o; o >>= 1) q += __shfl_xor(q, o);
    float var = q * (1.f / 64.f);
    float y = d * rsqrtf(var + 1e-5f) * cg[ln] + cbe[ln];
    sh1[wv][ln] = fmaxf(y, 0.f);
  }
  float l1v[3];
#pragma unroll
  for (int r = 0; r < 3; ++r) {
    int j = t + r * 256;
    float acc = B1[j];
    const float* w = W1 + (size_t)j * 768;
#pragma unroll 4
    for (int k = 0; k < 768; ++k) acc = fmaf(sctx[k], w[k], acc);
    l1v[r] = acc;
  }
  float S = blk_sum256(l1v[0] + l1v[1] + l1v[2], sr4);
  float mean = S * (1.f / 768.f);
  float q = 0.f;
#pragma unroll
  for (int r = 0; r < 3; ++r) { float d = l1v[r] - mean; q += d * d; }
  float var = blk_sum256(q, sr4) * (1.f / 768.f);
  float inv = rsqrtf(var + 1e-5f);
#pragma unroll
  for (int r = 0; r < 3; ++r) {
    int j = t + r * 256;
    float y = (l1v[r] - mean) * inv * Lg[j] + Lbe[j];
    sl1[j] = fmaxf(y, 0.f);
  }
  __syncthreads();
  if (wv < 3) {
    float acc = 0.f;
    for (int j = ln; j < 768; j += 64) acc = fmaf(sl1[j], W2[wv * 768 + j], acc);
    for (int o = 32; o; o >>= 1) acc += __shfl_xor(acc, o);
    if (ln == 0) slvlw[wv] = 1.f / (1.f + __expf(-(acc + B2[wv])));
  }
  __syncthreads();
  {
    int c2 = t;
    float a = 0.f;
#pragma unroll
    for (int g = 0; g < 3; ++g) {
      float acc = b2[c2];
      const float* w = w2 + c2 * 64;
#pragma unroll 4
      for (int j = 0; j < 64; ++j) acc = fmaf(sh1[g][j], w[j], acc);
      a += acc * slvlw[g];
    }
    addp[c2] = a;
  }
}

// K5: out[b,c2,:] += add[b,c2] (cached load: expect L3 hits on out); also copies x_last
__global__ __launch_bounds__(256) void k5_add(float* __restrict__ out,
                                              const float* __restrict__ add_all,
                                              const float* __restrict__ xlast) {
  size_t f4i = (size_t)blockIdx.x * 256 + threadIdx.x;
  if (f4i >= 11141120) {
    size_t r = f4i - 11141120;  // < 32768
    f4 v = *(const f4*)(xlast + (r << 2));
    ntstore(out + (f4i << 2), v);
    return;
  }
  int lvl, lgN2;
  size_t base;
  if (f4i < 8388608)       { lvl = 0; base = 0;        lgN2 = 12; }
  else if (f4i < 10485760) { lvl = 1; base = 8388608;  lgN2 = 10; }
  else if (f4i < 11010048) { lvl = 2; base = 10485760; lgN2 = 8;  }
  else                     { lvl = 3; base = 11010048; lgN2 = 6;  }
  size_t lf4 = f4i - base;
  int bc = (int)(lf4 >> lgN2);
  float a = add_all[lvl * 2048 + bc];
  float* p = out + (f4i << 2);
  f4 v = *(const f4*)p;
  v += a;
  ntstore(p, v);
}

extern "C" void kernel_launch(void* const* d_in, const int* in_sizes, int n_in,
                              void* d_out, int out_size, void* d_ws, size_t ws_size,
                              hipStream_t stream) {
  const float* gx[4] = {(const float*)d_in[0], (const float*)d_in[1],
                        (const float*)d_in[2], (const float*)d_in[3]};
  const float* x_last = (const float*)d_in[4];
  const float* w_qk = (const float*)d_in[5];
  // d_in[6] = b_qk: constant over softmax axis -> cancels, unused
  const float* ct_w1 = (const float*)d_in[7];
  const float* ct_b1 = (const float*)d_in[8];
  const float* ct_g  = (const float*)d_in[9];
  const float* ct_be = (const float*)d_in[10];
  const float* ct_w2 = (const float*)d_in[11];
  const float* ct_b2 = (const float*)d_in[12];
  const float* lw_w1 = (const float*)d_in[13];
  const float* lw_b1 = (const float*)d_in[14];
  const float* lw_g  = (const float*)d_in[15];
  const float* lw_be = (const float*)d_in[16];
  const float* lw_w2 = (const float*)d_in[17];
  const float* lw_b2 = (const float*)d_in[18];
  float* out = (float*)d_out;
  float* ws = (float*)d_ws;

  static const int Ns[4] = {16384, 4096, 1024, 256};
  static const int nt1[4] = {32, 8, 2, 1};    // N/512
  static const int nt2[4] = {16, 4, 1, 1};    // N/1024
  static const int logOff[4] = {0, 393216, 491520, 516096};
  static const size_t outOff[4] = {0, 33554432, 41943040, 44040192};

  float* partb = ws;                       // 2 * 522240
  float* zpart = ws + 2 * PART_STRIDE;     // 4*24*16 = 1536
  float* ctxb  = zpart + 1536;             // 4*8*768 = 24576
  float* addb  = ctxb + 24576;             // 4*8*256 = 8192

  K1Args a1;
  K2Args a2;
  K3Args a3;
  a1.part = partb;
  a2.part = partb;
  a2.zpart = zpart;
  a3.expl = partb;
  for (int i = 0; i < 4; ++i) {
    a1.x[i] = gx[i];
    a1.N[i] = Ns[i];
    a1.ntiles[i] = nt1[i];
    a1.logOff[i] = logOff[i];
    a2.N[i] = Ns[i];
    a2.ntiles2[i] = nt2[i];
    a2.logOff[i] = logOff[i];
    a3.x[i] = gx[i];
    a3.outp[i] = out + outOff[i];
    a3.ctx[i] = ctxb + i * 6144;
    a3.N[i] = Ns[i];
    a3.logOff[i] = logOff[i];
  }

  k1_partdot<<<dim3(32, 24, 8), dim3(128), 0, stream>>>(a1, w_qk);
  k2_exp<<<dim3(16, 24, 4), dim3(256), 0, stream>>>(a2);
  k3_ctx_out<<<dim3(256, NB, 4), dim3(256), 0, stream>>>(a3);
  k4_mlp<<<dim3(NB, 4), dim3(256), 0, stream>>>(ctxb, zpart, ct_w1, ct_b1, ct_g, ct_be,
                                                ct_w2, ct_b2, lw_w1, lw_b1, lw_g,
                                                lw_be, lw_w2, lw_b2, addb);
  k5_add<<<dim3(43648), dim3(256), 0, stream>>>(out, addb, x_last);
}

// Round 5
// 388.216 us; speedup vs baseline: 1.2949x; 1.2949x over previous
//
#include <hip/hip_runtime.h>

#define NB 8

typedef float f4 __attribute__((ext_vector_type(4)));

__device__ __forceinline__ f4 ntload(const float* p) {
  return __builtin_nontemporal_load((const f4*)p);
}
__device__ __forceinline__ void ntstore(float* p, f4 v) {
  __builtin_nontemporal_store(v, (f4*)p);
}
__device__ __forceinline__ float hsum(f4 v) { return v.x + v.y + v.z + v.w; }

struct K1Args {
  const float* x[4];
  float* expl;          // [522240] exp(logits), bg-major per level
  float* zpart;         // [4][24][32]
  int N[4];
  int ntiles[4];        // N/512 (min 1)
  int logOff[4];
};

struct K3Args {
  const float* x[4];
  const float* expl;
  float* outp[4];
  float* ctx[4];        // raw (unnormalized) sums [b][g][256]
  int N[4];
  int logOff[4];
};

// K1: full 256-channel logit -> exp -> expl (cached store) + per-tile Z partial.
// x loads NONTEMPORAL: 535 MB stream must not thrash L2/L3.
__global__ __launch_bounds__(128) void k1_logits(K1Args a, const float* __restrict__ wqk_all) {
  int lvl = blockIdx.z;
  if ((int)blockIdx.x >= a.ntiles[lvl]) return;
  int N = a.N[lvl];
  int bg = blockIdx.y, g = bg % 3, b = bg / 3;
  int n0 = blockIdx.x * 512 + (threadIdx.x << 2);
  float esum = 0.f;
  if (n0 < N) {
    const float* __restrict__ xb = a.x[lvl] + (size_t)b * 768 * N;
    const float* __restrict__ wqk = wqk_all + lvl * 256;
    f4 acc0 = {0.f, 0.f, 0.f, 0.f};
    f4 acc1 = {0.f, 0.f, 0.f, 0.f};
    int f0 = g * 256;
#pragma unroll 8
    for (int i = 0; i < 256; i += 2) {
      int f = f0 + i;
      int s0 = (f % 3) * 256 + f / 3;
      int s1 = ((f + 1) % 3) * 256 + (f + 1) / 3;
      f4 v0 = ntload(xb + (size_t)s0 * N + n0);
      f4 v1 = ntload(xb + (size_t)s1 * N + n0);
      acc0 += v0 * wqk[i];
      acc1 += v1 * wqk[i + 1];
    }
    f4 s = acc0 + acc1;
    f4 e;
    e.x = __expf(s.x); e.y = __expf(s.y); e.z = __expf(s.z); e.w = __expf(s.w);
    *(f4*)(a.expl + a.logOff[lvl] + (size_t)bg * N + n0) = e;
    esum = hsum(e);
  }
  for (int o = 32; o; o >>= 1) esum += __shfl_xor(esum, o);
  __shared__ float sr[2];
  if ((threadIdx.x & 63) == 0) sr[threadIdx.x >> 6] = esum;
  __syncthreads();
  if (threadIdx.x == 0)
    a.zpart[((size_t)lvl * 24 + bg) * 32 + blockIdx.x] = sr[0] + sr[1];
}

// K3: out[b,c2,n] = sum_g x[src(g,c2),n]  -- CACHED store (L3 retains out for K5)
//     ctxraw[b,g,c2] = sum_n x[src(g,c2),n] * expl[b,g,n]  (x loads NT)
__global__ __launch_bounds__(256) void k3_ctx_out(K3Args a) {
  int lvl = blockIdx.z;
  int N = a.N[lvl];
  int c2 = blockIdx.x, b = blockIdx.y;
  const float* __restrict__ xb = a.x[lvl] + (size_t)b * 768 * N;
  int f0 = c2, f1 = 256 + c2, f2 = 512 + c2;
  const float* __restrict__ r0 = xb + (size_t)((f0 % 3) * 256 + f0 / 3) * N;
  const float* __restrict__ r1 = xb + (size_t)((f1 % 3) * 256 + f1 / 3) * N;
  const float* __restrict__ r2 = xb + (size_t)((f2 % 3) * 256 + f2 / 3) * N;
  const float* __restrict__ eb = a.expl + a.logOff[lvl];
  const float* __restrict__ e0 = eb + (size_t)(b * 3 + 0) * N;
  const float* __restrict__ e1 = eb + (size_t)(b * 3 + 1) * N;
  const float* __restrict__ e2 = eb + (size_t)(b * 3 + 2) * N;
  float* __restrict__ o = a.outp[lvl] + ((size_t)b * 256 + c2) * N;
  float a0 = 0.f, a1 = 0.f, a2 = 0.f;
#pragma unroll 4
  for (int n = threadIdx.x << 2; n < N; n += 1024) {
    f4 v0 = ntload(r0 + n);
    f4 v1 = ntload(r1 + n);
    f4 v2 = ntload(r2 + n);
    f4 w0 = *(const f4*)(e0 + n);
    f4 w1 = *(const f4*)(e1 + n);
    f4 w2 = *(const f4*)(e2 + n);
    f4 ov = v0 + v1 + v2;
    *(f4*)(o + n) = ov;            // cached: L3 should hold out for K5
    f4 p0 = v0 * w0, p1 = v1 * w1, p2 = v2 * w2;
    a0 += hsum(p0);
    a1 += hsum(p1);
    a2 += hsum(p2);
  }
  for (int o2 = 32; o2; o2 >>= 1) {
    a0 += __shfl_xor(a0, o2);
    a1 += __shfl_xor(a1, o2);
    a2 += __shfl_xor(a2, o2);
  }
  __shared__ float sr[3][4];
  int wv = threadIdx.x >> 6;
  if ((threadIdx.x & 63) == 0) { sr[0][wv] = a0; sr[1][wv] = a1; sr[2][wv] = a2; }
  __syncthreads();
  if (threadIdx.x < 3) {
    int t = threadIdx.x;
    float s = sr[t][0] + sr[t][1] + sr[t][2] + sr[t][3];
    a.ctx[lvl][((size_t)b * 3 + t) * 256 + c2] = s;
  }
}

__device__ __forceinline__ float blk_sum256(float v, float* sr4) {
  for (int o = 32; o; o >>= 1) v += __shfl_xor(v, o);
  __syncthreads();
  if ((threadIdx.x & 63) == 0) sr4[threadIdx.x >> 6] = v;
  __syncthreads();
  return sr4[0] + sr4[1] + sr4[2] + sr4[3];
}

// K4: sum Z partials, normalize ctx, ct-MLP + lvl-weight MLP -> add (f4-vectorized GEMVs)
__global__ __launch_bounds__(256) void k4_mlp(
    const float* __restrict__ ctx_all, const float* __restrict__ zpart,
    const float* __restrict__ ct_w1, const float* __restrict__ ct_b1,
    const float* __restrict__ ct_g,  const float* __restrict__ ct_be,
    const float* __restrict__ ct_w2, const float* __restrict__ ct_b2,
    const float* __restrict__ lw_w1, const float* __restrict__ lw_b1,
    const float* __restrict__ lw_g,  const float* __restrict__ lw_be,
    const float* __restrict__ lw_w2, const float* __restrict__ lw_b2,
    float* __restrict__ add_all) {
  int b = blockIdx.x, lvl = blockIdx.y;
  int t = threadIdx.x;
  const float* cin = ctx_all + ((size_t)lvl * NB + b) * 768;
  const float* w1 = ct_w1 + lvl * 64 * 256;
  const float* b1 = ct_b1 + lvl * 64;
  const float* cg = ct_g + lvl * 64;
  const float* cbe = ct_be + lvl * 64;
  const float* w2 = ct_w2 + lvl * 256 * 64;
  const float* b2 = ct_b2 + lvl * 256;
  const float* W1 = lw_w1 + (size_t)lvl * 768 * 768;
  const float* B1 = lw_b1 + lvl * 768;
  const float* Lg = lw_g + lvl * 768;
  const float* Lbe = lw_be + lvl * 768;
  const float* W2 = lw_w2 + lvl * 3 * 768;
  const float* B2 = lw_b2 + lvl * 3;
  float* addp = add_all + ((size_t)lvl * NB + b) * 256;

  __shared__ float sctx[768];
  __shared__ float sh1[3][64];
  __shared__ float sl1[768];
  __shared__ float slvlw[3];
  __shared__ float sr4[4];
  __shared__ float sZ[3];

  int nt = 32 >> (2 * lvl);
  if (nt < 1) nt = 1;
  if (t < 3) {
    const float* zp = zpart + ((size_t)lvl * 24 + b * 3 + t) * 32;
    float z = 0.f;
    for (int i = 0; i < nt; ++i) z += zp[i];
    sZ[t] = z;
  }
  __syncthreads();
  for (int i = t; i < 768; i += 256) sctx[i] = cin[i] / sZ[i >> 8];
  __syncthreads();

  if (t < 192) {
    int g = t >> 6, j = t & 63;
    const f4* w4 = (const f4*)(w1 + j * 256);
    const f4* c4 = (const f4*)(sctx + g * 256);
    f4 acc = {0.f, 0.f, 0.f, 0.f};
#pragma unroll 8
    for (int k = 0; k < 64; ++k) acc += c4[k] * w4[k];
    sh1[g][j] = hsum(acc) + b1[j];
  }
  __syncthreads();
  int wv = t >> 6, ln = t & 63;
  if (wv < 3) {
    float v = sh1[wv][ln];
    float s = v;
    for (int o = 32; o; o >>= 1) s += __shfl_xor(s, o);
    float mean = s * (1.f / 64.f);
    float d = v - mean;
    float q = d * d;
    for (int o = 32; o; o >>= 1) q += __shfl_xor(q, o);
    float var = q * (1.f / 64.f);
    float y = d * rsqrtf(var + 1e-5f) * cg[ln] + cbe[ln];
    sh1[wv][ln] = fmaxf(y, 0.f);
  }
  __syncthreads();
  float l1v[3];
#pragma unroll
  for (int r = 0; r < 3; ++r) {
    int j = t + r * 256;
    const f4* W4 = (const f4*)(W1 + (size_t)j * 768);
    const f4* s4 = (const f4*)sctx;
    f4 acc = {0.f, 0.f, 0.f, 0.f};
#pragma unroll 8
    for (int k = 0; k < 192; ++k) acc += s4[k] * W4[k];
    l1v[r] = hsum(acc) + B1[j];
  }
  float S = blk_sum256(l1v[0] + l1v[1] + l1v[2], sr4);
  float mean = S * (1.f / 768.f);
  float q = 0.f;
#pragma unroll
  for (int r = 0; r < 3; ++r) { float d = l1v[r] - mean; q += d * d; }
  float var = blk_sum256(q, sr4) * (1.f / 768.f);
  float inv = rsqrtf(var + 1e-5f);
#pragma unroll
  for (int r = 0; r < 3; ++r) {
    int j = t + r * 256;
    float y = (l1v[r] - mean) * inv * Lg[j] + Lbe[j];
    sl1[j] = fmaxf(y, 0.f);
  }
  __syncthreads();
  if (wv < 3) {
    float acc = 0.f;
    for (int j = ln; j < 768; j += 64) acc = fmaf(sl1[j], W2[wv * 768 + j], acc);
    for (int o = 32; o; o >>= 1) acc += __shfl_xor(acc, o);
    if (ln == 0) slvlw[wv] = 1.f / (1.f + __expf(-(acc + B2[wv])));
  }
  __syncthreads();
  {
    int c2 = t;
    float a = 0.f;
#pragma unroll
    for (int g = 0; g < 3; ++g) {
      const f4* w4 = (const f4*)(w2 + c2 * 64);
      const f4* h4 = (const f4*)(sh1[g]);
      f4 acc = {0.f, 0.f, 0.f, 0.f};
#pragma unroll
      for (int j = 0; j < 16; ++j) acc += h4[j] * w4[j];
      a += (hsum(acc) + b2[c2]) * slvlw[g];
    }
    addp[c2] = a;
  }
}

// K5: out[b,c2,:] += add[b,c2]  (cached out load -> L3 hits; nt store) + x_last copy
__global__ __launch_bounds__(256) void k5_add(float* __restrict__ out,
                                              const float* __restrict__ add_all,
                                              const float* __restrict__ xlast) {
  size_t f4i = (size_t)blockIdx.x * 256 + threadIdx.x;
  if (f4i >= 11141120) {
    size_t r = f4i - 11141120;  // < 32768
    f4 v = ntload(xlast + (r << 2));
    ntstore(out + (f4i << 2), v);
    return;
  }
  int lvl, lgN2;
  size_t base;
  if (f4i < 8388608)       { lvl = 0; base = 0;        lgN2 = 12; }
  else if (f4i < 10485760) { lvl = 1; base = 8388608;  lgN2 = 10; }
  else if (f4i < 11010048) { lvl = 2; base = 10485760; lgN2 = 8;  }
  else                     { lvl = 3; base = 11010048; lgN2 = 6;  }
  size_t lf4 = f4i - base;
  int bc = (int)(lf4 >> lgN2);
  float a = add_all[lvl * 2048 + bc];
  float* p = out + (f4i << 2);
  f4 v = *(const f4*)p;   // cached load: expect L3 hit on out written by K3
  v += a;
  ntstore(p, v);
}

extern "C" void kernel_launch(void* const* d_in, const int* in_sizes, int n_in,
                              void* d_out, int out_size, void* d_ws, size_t ws_size,
                              hipStream_t stream) {
  const float* gx[4] = {(const float*)d_in[0], (const float*)d_in[1],
                        (const float*)d_in[2], (const float*)d_in[3]};
  const float* x_last = (const float*)d_in[4];
  const float* w_qk = (const float*)d_in[5];
  // d_in[6] = b_qk: constant over softmax axis -> cancels, unused
  const float* ct_w1 = (const float*)d_in[7];
  const float* ct_b1 = (const float*)d_in[8];
  const float* ct_g  = (const float*)d_in[9];
  const float* ct_be = (const float*)d_in[10];
  const float* ct_w2 = (const float*)d_in[11];
  const float* ct_b2 = (const float*)d_in[12];
  const float* lw_w1 = (const float*)d_in[13];
  const float* lw_b1 = (const float*)d_in[14];
  const float* lw_g  = (const float*)d_in[15];
  const float* lw_be = (const float*)d_in[16];
  const float* lw_w2 = (const float*)d_in[17];
  const float* lw_b2 = (const float*)d_in[18];
  float* out = (float*)d_out;
  float* ws = (float*)d_ws;

  static const int Ns[4] = {16384, 4096, 1024, 256};
  static const int nt1[4] = {32, 8, 2, 1};    // N/512
  static const int logOff[4] = {0, 393216, 491520, 516096};
  static const size_t outOff[4] = {0, 33554432, 41943040, 44040192};

  float* explb = ws;                  // 522240
  float* zpart = ws + 522240;         // 4*24*32 = 3072
  float* ctxb  = zpart + 3072;        // 4*8*768 = 24576
  float* addb  = ctxb + 24576;        // 4*8*256 = 8192

  K1Args a1;
  K3Args a3;
  a1.expl = explb;
  a1.zpart = zpart;
  a3.expl = explb;
  for (int i = 0; i < 4; ++i) {
    a1.x[i] = gx[i];
    a1.N[i] = Ns[i];
    a1.ntiles[i] = nt1[i];
    a1.logOff[i] = logOff[i];
    a3.x[i] = gx[i];
    a3.outp[i] = out + outOff[i];
    a3.ctx[i] = ctxb + i * 6144;
    a3.N[i] = Ns[i];
    a3.logOff[i] = logOff[i];
  }

  k1_logits<<<dim3(32, 24, 4), dim3(128), 0, stream>>>(a1, w_qk);
  k3_ctx_out<<<dim3(256, NB, 4), dim3(256), 0, stream>>>(a3);
  k4_mlp<<<dim3(NB, 4), dim3(256), 0, stream>>>(ctxb, zpart, ct_w1, ct_b1, ct_g, ct_be,
                                                ct_w2, ct_b2, lw_w1, lw_b1, lw_g,
                                                lw_be, lw_w2, lw_b2, addb);
  k5_add<<<dim3(43648), dim3(256), 0, stream>>>(out, addb, x_last);
}

// Round 6
// 298.359 us; speedup vs baseline: 1.6848x; 1.3012x over previous
//
#include <hip/hip_runtime.h>

#define NB 8
#define T 32          // spatial tile width (floats)
#define TPW 8         // tiles per workgroup
#define NWG 680       // total fused workgroups
#define PSTRIDE 772   // 768 ctx + 3 z + 1 pad

typedef float f4 __attribute__((ext_vector_type(4)));

__device__ __forceinline__ f4 ntload(const float* p) {
  return __builtin_nontemporal_load((const f4*)p);
}
__device__ __forceinline__ void ntstore(float* p, f4 v) {
  __builtin_nontemporal_store(v, (f4*)p);
}
__device__ __forceinline__ float hsum(f4 v) { return v.x + v.y + v.z + v.w; }

struct KFArgs {
  const float* x[4];
  float* outp[4];
  float* partial;     // [NWG][PSTRIDE]
  int N[4];
};

// Fused kernel: one pass over x.
// Per wg: 8 consecutive 32-col tiles of one (lvl,b).
// LDS xt[768][32] holds the shuffled-channel tile; per tile:
//   stage -> logits(threads<256) || out-write(threads>=256) -> exp -> ctx accumulate.
// ctx/z accumulated in registers across tiles; one partial row per wg.
__global__ __launch_bounds__(512) void kf_fused(KFArgs a, const float* __restrict__ wqk_all) {
  extern __shared__ float lds[];
  float* xt   = lds;                 // [768*32]
  float* swq  = xt + 768 * T;        // [256]
  float* red  = swq + 256;           // [8][3][32]
  float* se   = red + 768;           // [3][32]
  float* zred = se + 96;             // [96]

  int wg = blockIdx.x;
  int lvl, b, t0;
  if (wg < 512)      { lvl = 0; b = wg >> 6;        t0 = (wg & 63) * TPW; }
  else if (wg < 640) { int r = wg - 512; lvl = 1; b = r >> 4; t0 = (r & 15) * TPW; }
  else if (wg < 672) { int r = wg - 640; lvl = 2; b = r >> 2; t0 = (r & 3) * TPW; }
  else               { int r = wg - 672; lvl = 3; b = r;      t0 = 0; }
  int N = a.N[lvl];
  const float* __restrict__ xb = a.x[lvl] + (size_t)b * 768 * N;
  float* __restrict__ outb = a.outp[lvl] + (size_t)b * 256 * N;
  int tid = threadIdx.x;

  if (tid < 256) swq[tid] = wqk_all[lvl * 256 + tid];

  float accA = 0.f, accB = 0.f;  // ctx for ch=tid and ch=tid+512 (tid<256)
  float zacc = 0.f;              // threads<96: per-(g,n) z accumulator

  int snq = tid & 7, srow0 = tid >> 3;  // staging: 8 lanes per row-chunk (128B)
  f4 reg[12];
  {
    int n0 = t0 * T;
#pragma unroll
    for (int i = 0; i < 12; ++i) {
      int s = srow0 + i * 64;
      reg[i] = ntload(xb + (size_t)s * N + n0 + snq * 4);
    }
  }

  for (int tt = 0; tt < TPW; ++tt) {
    int n0 = (t0 + tt) * T;
    __syncthreads();  // xt free (previous ctx done)
#pragma unroll
    for (int i = 0; i < 12; ++i) {
      int s = srow0 + i * 64;
      int f = (s & 255) * 3 + (s >> 8);   // channel-shuffle: store by f-index
      *(f4*)(xt + f * T + snq * 4) = reg[i];
    }
    __syncthreads();  // xt staged
    if (tid < 256) {
      // logit partials: (n, cb) each does 32 channels for all 3 g
      int n = tid & 31, cb = tid >> 5;
      float l0 = 0.f, l1 = 0.f, l2 = 0.f;
      const float* w = swq + cb * 32;
      const float* base = xt + (cb * 32) * T + n;
#pragma unroll 8
      for (int c = 0; c < 32; ++c) {
        float wv = w[c];
        l0 = fmaf(base[c * T], wv, l0);
        l1 = fmaf(base[(256 + c) * T], wv, l1);
        l2 = fmaf(base[(512 + c) * T], wv, l2);
      }
      red[cb * 96 + 0 * 32 + n] = l0;
      red[cb * 96 + 1 * 32 + n] = l1;
      red[cb * 96 + 2 * 32 + n] = l2;
    } else {
      // out write: item=(c2,nq), cached store (L3 retains out for K5)
      int t2 = tid - 256;
#pragma unroll
      for (int k = 0; k < 8; ++k) {
        int item = t2 + k * 256;
        int c2 = item >> 3, nq = item & 7;
        const float* p = xt + c2 * T + nq * 4;
        f4 v = *(const f4*)p + *(const f4*)(p + 256 * T) + *(const f4*)(p + 512 * T);
        *(f4*)(outb + (size_t)c2 * N + n0 + nq * 4) = v;
      }
    }
    __syncthreads();  // red complete
    if (tid < 96) {
      int g = tid >> 5, n = tid & 31;
      float l = 0.f;
#pragma unroll
      for (int cb = 0; cb < 8; ++cb) l += red[cb * 96 + g * 32 + n];
      float e = __expf(l);
      se[g * 32 + n] = e;
      zacc += e;
    }
    __syncthreads();  // se ready
    // prefetch next tile (flies during ctx phase)
    if (tt + 1 < TPW) {
      int n0n = (t0 + tt + 1) * T;
#pragma unroll
      for (int i = 0; i < 12; ++i) {
        int s = srow0 + i * 64;
        reg[i] = ntload(xb + (size_t)s * N + n0n + snq * 4);
      }
    }
    // ctx accumulate (rotation keeps banks spread)
    {
      int lane = tid & 63;
      int g = tid >> 8;
      const float* xr = xt + tid * T;
      const float* er = se + g * 32;
      float acc = 0.f;
#pragma unroll 8
      for (int i = 0; i < 32; ++i) {
        int nn = (i + lane) & 31;
        acc = fmaf(xr[nn], er[nn], acc);
      }
      accA += acc;
      if (tid < 256) {
        const float* xr2 = xt + (tid + 512) * T;
        const float* er2 = se + 64;
        float acc2 = 0.f;
#pragma unroll 8
        for (int i = 0; i < 32; ++i) {
          int nn = (i + lane) & 31;
          acc2 = fmaf(xr2[nn], er2[nn], acc2);
        }
        accB += acc2;
      }
    }
  }
  // write per-wg partials (deterministic)
  float* pw = a.partial + (size_t)wg * PSTRIDE;
  pw[tid] = accA;
  if (tid < 256) pw[tid + 512] = accB;
  if (tid < 96) zred[tid] = zacc;
  __syncthreads();
  if (tid < 3) {
    float z = 0.f;
#pragma unroll
    for (int i = 0; i < 32; ++i) z += zred[tid * 32 + i];
    pw[768 + tid] = z;
  }
}

__device__ __forceinline__ float blk_sum256(float v, float* sr4) {
  for (int o = 32; o; o >>= 1) v += __shfl_xor(v, o);
  __syncthreads();
  if ((threadIdx.x & 63) == 0) sr4[threadIdx.x >> 6] = v;
  __syncthreads();
  return sr4[0] + sr4[1] + sr4[2] + sr4[3];
}

// K4: reduce wg partials -> ctx (normalized), then ct-MLP + lvl-weight MLP -> add
__global__ __launch_bounds__(256) void k4_mlp(
    const float* __restrict__ partial,
    const float* __restrict__ ct_w1, const float* __restrict__ ct_b1,
    const float* __restrict__ ct_g,  const float* __restrict__ ct_be,
    const float* __restrict__ ct_w2, const float* __restrict__ ct_b2,
    const float* __restrict__ lw_w1, const float* __restrict__ lw_b1,
    const float* __restrict__ lw_g,  const float* __restrict__ lw_be,
    const float* __restrict__ lw_w2, const float* __restrict__ lw_b2,
    float* __restrict__ add_all) {
  int b = blockIdx.x, lvl = blockIdx.y;
  int t = threadIdx.x;
  static const int cnt_[4] = {64, 16, 4, 1};
  static const int base_[4] = {0, 512, 640, 672};
  int cnt = cnt_[lvl];
  int wg0 = base_[lvl] + b * cnt;

  const float* w1 = ct_w1 + lvl * 64 * 256;
  const float* b1 = ct_b1 + lvl * 64;
  const float* cg = ct_g + lvl * 64;
  const float* cbe = ct_be + lvl * 64;
  const float* w2 = ct_w2 + lvl * 256 * 64;
  const float* b2 = ct_b2 + lvl * 256;
  const float* W1 = lw_w1 + (size_t)lvl * 768 * 768;
  const float* B1 = lw_b1 + lvl * 768;
  const float* Lg = lw_g + lvl * 768;
  const float* Lbe = lw_be + lvl * 768;
  const float* W2 = lw_w2 + lvl * 3 * 768;
  const float* B2 = lw_b2 + lvl * 3;
  float* addp = add_all + ((size_t)lvl * NB + b) * 256;

  __shared__ float sctx[768];
  __shared__ float sh1[3][64];
  __shared__ float sl1[768];
  __shared__ float slvlw[3];
  __shared__ float sr4[4];
  __shared__ float sZ[3];

  // reduce partials (fixed order -> deterministic)
  float s0 = 0.f, s1 = 0.f, s2 = 0.f;
  for (int w = 0; w < cnt; ++w) {
    const float* pw = partial + (size_t)(wg0 + w) * PSTRIDE;
    s0 += pw[t];
    s1 += pw[t + 256];
    s2 += pw[t + 512];
  }
  if (t < 3) {
    float z = 0.f;
    for (int w = 0; w < cnt; ++w) z += partial[(size_t)(wg0 + w) * PSTRIDE + 768 + t];
    sZ[t] = z;
  }
  __syncthreads();
  sctx[t] = s0 / sZ[0];
  sctx[t + 256] = s1 / sZ[1];
  sctx[t + 512] = s2 / sZ[2];
  __syncthreads();

  if (t < 192) {
    int g = t >> 6, j = t & 63;
    const f4* w4 = (const f4*)(w1 + j * 256);
    const f4* c4 = (const f4*)(sctx + g * 256);
    f4 acc = {0.f, 0.f, 0.f, 0.f};
#pragma unroll 8
    for (int k = 0; k < 64; ++k) acc += c4[k] * w4[k];
    sh1[g][j] = hsum(acc) + b1[j];
  }
  __syncthreads();
  int wv = t >> 6, ln = t & 63;
  if (wv < 3) {
    float v = sh1[wv][ln];
    float s = v;
    for (int o = 32; o; o >>= 1) s += __shfl_xor(s, o);
    float mean = s * (1.f / 64.f);
    float d = v - mean;
    float q = d * d;
    for (int o = 32; o; o >>= 1) q += __shfl_xor(q, o);
    float var = q * (1.f / 64.f);
    float y = d * rsqrtf(var + 1e-5f) * cg[ln] + cbe[ln];
    sh1[wv][ln] = fmaxf(y, 0.f);
  }
  __syncthreads();
  float l1v[3];
#pragma unroll
  for (int r = 0; r < 3; ++r) {
    int j = t + r * 256;
    const f4* W4 = (const f4*)(W1 + (size_t)j * 768);
    const f4* s4 = (const f4*)sctx;
    f4 acc = {0.f, 0.f, 0.f, 0.f};
#pragma unroll 8
    for (int k = 0; k < 192; ++k) acc += s4[k] * W4[k];
    l1v[r] = hsum(acc) + B1[j];
  }
  float S = blk_sum256(l1v[0] + l1v[1] + l1v[2], sr4);
  float mean = S * (1.f / 768.f);
  float q = 0.f;
#pragma unroll
  for (int r = 0; r < 3; ++r) { float d = l1v[r] - mean; q += d * d; }
  float var = blk_sum256(q, sr4) * (1.f / 768.f);
  float inv = rsqrtf(var + 1e-5f);
#pragma unroll
  for (int r = 0; r < 3; ++r) {
    int j = t + r * 256;
    float y = (l1v[r] - mean) * inv * Lg[j] + Lbe[j];
    sl1[j] = fmaxf(y, 0.f);
  }
  __syncthreads();
  if (wv < 3) {
    float acc = 0.f;
    for (int j = ln; j < 768; j += 64) acc = fmaf(sl1[j], W2[wv * 768 + j], acc);
    for (int o = 32; o; o >>= 1) acc += __shfl_xor(acc, o);
    if (ln == 0) slvlw[wv] = 1.f / (1.f + __expf(-(acc + B2[wv])));
  }
  __syncthreads();
  {
    int c2 = t;
    float a = 0.f;
#pragma unroll
    for (int g = 0; g < 3; ++g) {
      const f4* w4 = (const f4*)(w2 + c2 * 64);
      const f4* h4 = (const f4*)(sh1[g]);
      f4 acc = {0.f, 0.f, 0.f, 0.f};
#pragma unroll
      for (int j = 0; j < 16; ++j) acc += h4[j] * w4[j];
      a += (hsum(acc) + b2[c2]) * slvlw[g];
    }
    addp[c2] = a;
  }
}

// K5: out[b,c2,:] += add[b,c2]  (cached out load -> L3 hits; nt store) + x_last copy
__global__ __launch_bounds__(256) void k5_add(float* __restrict__ out,
                                              const float* __restrict__ add_all,
                                              const float* __restrict__ xlast) {
  size_t f4i = (size_t)blockIdx.x * 256 + threadIdx.x;
  if (f4i >= 11141120) {
    size_t r = f4i - 11141120;  // < 32768
    f4 v = ntload(xlast + (r << 2));
    ntstore(out + (f4i << 2), v);
    return;
  }
  int lvl, lgN2;
  size_t base;
  if (f4i < 8388608)       { lvl = 0; base = 0;        lgN2 = 12; }
  else if (f4i < 10485760) { lvl = 1; base = 8388608;  lgN2 = 10; }
  else if (f4i < 11010048) { lvl = 2; base = 10485760; lgN2 = 8;  }
  else                     { lvl = 3; base = 11010048; lgN2 = 6;  }
  size_t lf4 = f4i - base;
  int bc = (int)(lf4 >> lgN2);
  float a = add_all[lvl * 2048 + bc];
  float* p = out + (f4i << 2);
  f4 v = *(const f4*)p;  // cached: expect L3 hit on out written by kf_fused
  v += a;
  ntstore(p, v);
}

extern "C" void kernel_launch(void* const* d_in, const int* in_sizes, int n_in,
                              void* d_out, int out_size, void* d_ws, size_t ws_size,
                              hipStream_t stream) {
  const float* gx[4] = {(const float*)d_in[0], (const float*)d_in[1],
                        (const float*)d_in[2], (const float*)d_in[3]};
  const float* x_last = (const float*)d_in[4];
  const float* w_qk = (const float*)d_in[5];
  // d_in[6] = b_qk: constant over softmax axis -> cancels, unused
  const float* ct_w1 = (const float*)d_in[7];
  const float* ct_b1 = (const float*)d_in[8];
  const float* ct_g  = (const float*)d_in[9];
  const float* ct_be = (const float*)d_in[10];
  const float* ct_w2 = (const float*)d_in[11];
  const float* ct_b2 = (const float*)d_in[12];
  const float* lw_w1 = (const float*)d_in[13];
  const float* lw_b1 = (const float*)d_in[14];
  const float* lw_g  = (const float*)d_in[15];
  const float* lw_be = (const float*)d_in[16];
  const float* lw_w2 = (const float*)d_in[17];
  const float* lw_b2 = (const float*)d_in[18];
  float* out = (float*)d_out;
  float* ws = (float*)d_ws;

  static const int Ns[4] = {16384, 4096, 1024, 256};
  static const size_t outOff[4] = {0, 33554432, 41943040, 44040192};

  float* partb = ws;                          // NWG*PSTRIDE = 524960 floats
  float* addb  = ws + NWG * PSTRIDE;          // 4*8*256 = 8192 floats

  KFArgs af;
  for (int i = 0; i < 4; ++i) {
    af.x[i] = gx[i];
    af.outp[i] = out + outOff[i];
    af.N[i] = Ns[i];
  }
  af.partial = partb;

  const int ldsBytes = (768 * T + 256 + 768 + 96 + 96) * 4;  // 103168
  static int attrSet = 0;
  if (!attrSet) {
    (void)hipFuncSetAttribute((const void*)kf_fused,
                              hipFuncAttributeMaxDynamicSharedMemorySize, ldsBytes);
    attrSet = 1;
  }

  kf_fused<<<dim3(NWG), dim3(512), ldsBytes, stream>>>(af, w_qk);
  k4_mlp<<<dim3(NB, 4), dim3(256), 0, stream>>>(partb, ct_w1, ct_b1, ct_g, ct_be,
                                                ct_w2, ct_b2, lw_w1, lw_b1, lw_g,
                                                lw_be, lw_w2, lw_b2, addb);
  k5_add<<<dim3(43648), dim3(256), 0, stream>>>(out, addb, x_last);
}